// Round 2
// baseline (13829.227 us; speedup 1.0000x reference)
//
#include <hip/hip_runtime.h>
#include <climits>
#include <cmath>

// Greedy autoregressive LSTM decoder, persistent cooperative kernel.
// 256 blocks x 512 threads, 1 block/CU, flag-based grid barrier (2/step).
// All fp32 (no fp32 MFMA on CDNA4; bf16 would risk argmax flips that cascade).

#define NBLK 256
#define NTHR 512
#define WPB  8                      // waves per block
#define Bb 16
#define Hh 1024
#define Vv 32000
#define Tt 128
#define PITCH 1028                  // LDS row pitch (floats)

typedef float v4f __attribute__((ext_vector_type(4)));

__device__ __forceinline__ float dot4f(v4f a, v4f b, float acc) {
  return fmaf(a.x, b.x, fmaf(a.y, b.y, fmaf(a.z, b.z, fmaf(a.w, b.w, acc))));
}

__device__ __forceinline__ void online_upd(float& m, float& s, int& idx, float v, int r) {
  if (v > m) { s = s * __expf(m - v) + 1.0f; m = v; idx = r; }   // strict > keeps first-max
  else       { s += __expf(v - m); }
}

__device__ __forceinline__ void merge_ms(float& m, float& s, int& idx,
                                         float m2, float s2, int i2) {
  if (m2 > m)       { s = s * __expf(m - m2) + s2; m = m2; idx = i2; }
  else if (m2 == m) { s += s2; idx = (i2 < idx) ? i2 : idx; }     // np.argmax: first index
  else              { s = fmaf(s2, __expf(m2 - m), s); }
}

// Flag-based grid barrier: no same-address RMW contention.
// Each block release-stores its padded flag; block 0 polls all flags
// (relaxed agent loads = sc1, always fresh), then release-stores gen.
// Everyone acquire-fences (__threadfence) after its spin.
__device__ __forceinline__ void grid_barrier(int* flags, int* gen, int epoch) {
  __syncthreads();                       // drains each wave's vmem before flag
  if (threadIdx.x == 0) {
    __hip_atomic_store(&flags[blockIdx.x * 16], epoch,
                       __ATOMIC_RELEASE, __HIP_MEMORY_SCOPE_AGENT);
  }
  if (blockIdx.x == 0) {
    if (threadIdx.x < 64) {
      int base = threadIdx.x * 4;
      for (;;) {
        bool done = true;
#pragma unroll
        for (int k = 0; k < 4; ++k) {
          int v = __hip_atomic_load(&flags[(base + k) * 16],
                                    __ATOMIC_RELAXED, __HIP_MEMORY_SCOPE_AGENT);
          done &= (v >= epoch);
        }
        if (done) break;
        __builtin_amdgcn_s_sleep(2);
      }
    }
    __syncthreads();
    if (threadIdx.x == 0) {
      __threadfence();                   // acquire all blocks' released data
      __hip_atomic_store(gen, epoch, __ATOMIC_RELEASE, __HIP_MEMORY_SCOPE_AGENT);
    }
  } else {
    if (threadIdx.x == 0) {
      while (__hip_atomic_load(gen, __ATOMIC_RELAXED, __HIP_MEMORY_SCOPE_AGENT) < epoch) {
        __builtin_amdgcn_s_sleep(2);
      }
      __threadfence();                   // acquire
    }
  }
  __syncthreads();
}

extern "C" __global__ void __launch_bounds__(NTHR, 2)
decoder_rnn_kernel(const float* __restrict__ enc_h,
                   const float* __restrict__ enc_c,
                   const float* __restrict__ emb,
                   const float* __restrict__ Wih,
                   const float* __restrict__ Whh,
                   const float* __restrict__ bih,
                   const float* __restrict__ bhh,
                   const float* __restrict__ Wlin,
                   const float* __restrict__ blin,
                   float* __restrict__ out,
                   int* flags, int* gen,
                   float* hb0, float* hb1, float* cbuf,
                   float* pm, float* ps, int* pidx)
{
  __shared__ float x_sh[Bb * PITCH];          // 64.25 KB
  __shared__ float h_sh[Bb * PITCH];          // 64.25 KB
  __shared__ float gpart[WPB][8][Bb];         // 4 KB
  __shared__ float bm_[WPB][Bb];
  __shared__ float bs_[WPB][Bb];
  __shared__ int   bi_[WPB][Bb];
  __shared__ int   tk_sh[Bb];
  __shared__ float nm_sh[Bb];

  const int tid  = threadIdx.x;
  const int lane = tid & 63;
  const int wid  = tid >> 6;
  const int q    = lane >> 4;     // k-quarter 0..3
  const int b    = lane & 15;     // batch row
  const int bid  = blockIdx.x;
  const int wgl  = bid * WPB + wid;           // 0..2047; 2000 active for logits
  int ep = 0;

  float accL[4][4];               // this wave's 16 logit rows (raw, incl. bias)
#pragma unroll
  for (int g = 0; g < 4; ++g)
#pragma unroll
    for (int r = 0; r < 4; ++r) accL[g][r] = 0.f;

  // prologue: stage h(= enc_h) into LDS once; reused by gates of t=0
  for (int i = tid; i < Bb * (Hh / 4); i += NTHR) {
    int bb = i >> 8, k4 = i & 255;
    v4f hv = reinterpret_cast<const v4f*>(enc_h + (size_t)bb * Hh)[k4];
    *reinterpret_cast<v4f*>(&h_sh[bb * PITCH + k4 * 4]) = hv;
  }

  for (int t = 0; t < Tt; ++t) {
    float* hcur = (t & 1) ? hb1 : hb0;

    // ================= phase A =================
    // (a) self-reduce block partials of step t-1 -> tok, norm (per block, in LDS)
    if (t > 0) {
      int g = tid >> 5, l = tid & 31;      // g = batch, l = chunk lane
      float m = -__builtin_inff(); float s = 0.f; int ix = INT_MAX;
      for (int wb = l; wb < NBLK; wb += 32)
        merge_ms(m, s, ix, pm[wb * Bb + g], ps[wb * Bb + g], pidx[wb * Bb + g]);
#pragma unroll
      for (int off = 16; off; off >>= 1) {
        float m2 = __shfl_xor(m, off, 32);
        float s2 = __shfl_xor(s, off, 32);
        int   i2 = __shfl_xor(ix, off, 32);
        merge_ms(m, s, ix, m2, s2, i2);
      }
      if (l == 0) { tk_sh[g] = ix; nm_sh[g] = m + logf(s); }
    } else {
      if (tid < Bb) tk_sh[tid] = 1;        // SOS
    }
    __syncthreads();

    // (b) write normalized logits of step t-1 (registers + nm_sh)
    if (t > 0 && wgl < 2000 && q == 0) {
      float nb = nm_sh[b];
      size_t obase = ((size_t)b * Tt + (t - 1)) * (size_t)Vv;
#pragma unroll
      for (int g = 0; g < 4; ++g) {
        int rbase = wgl * 16 + g * 4;
        v4f vo;
        vo.x = accL[g][0] - nb; vo.y = accL[g][1] - nb;
        vo.z = accL[g][2] - nb; vo.w = accL[g][3] - nb;
        __builtin_nontemporal_store(vo, reinterpret_cast<v4f*>(out + obase + rbase));
      }
    }
    // (c) stage x = embedding[tok] into LDS (h_sh already holds h_{t-1})
    for (int i = tid; i < Bb * (Hh / 4); i += NTHR) {
      int bb = i >> 8, k4 = i & 255;
      int tk = tk_sh[bb];
      v4f xv = reinterpret_cast<const v4f*>(emb + (size_t)tk * Hh)[k4];
      *reinterpret_cast<v4f*>(&x_sh[bb * PITCH + k4 * 4]) = xv;
    }
    __syncthreads();

    // (d) gates dots: wave pair (wid&1 = K-half) handles j = bid*4 + (wid>>1)
    {
      const int j  = bid * 4 + (wid >> 1);
      const int kh = wid & 1;
      const int kb4 = kh * 128 + q * 32;          // float4 idx within row
      const v4f* wi0 = reinterpret_cast<const v4f*>(Wih) + (size_t)j * 256 + kb4;
      const v4f* wi1 = wi0 + (size_t)Hh * 256;
      const v4f* wi2 = wi1 + (size_t)Hh * 256;
      const v4f* wi3 = wi2 + (size_t)Hh * 256;
      const v4f* wh0 = reinterpret_cast<const v4f*>(Whh) + (size_t)j * 256 + kb4;
      const v4f* wh1 = wh0 + (size_t)Hh * 256;
      const v4f* wh2 = wh1 + (size_t)Hh * 256;
      const v4f* wh3 = wh2 + (size_t)Hh * 256;
      const float* xb  = &x_sh[b * PITCH + kh * 512 + q * 128];
      const float* hbp = &h_sh[b * PITCH + kh * 512 + q * 128];
      float a0=0,a1=0,a2=0,a3=0,a4=0,a5=0,a6=0,a7=0;
#pragma unroll 2
      for (int i = 0; i < 32; ++i) {
        v4f xv = *reinterpret_cast<const v4f*>(xb + i * 4);
        v4f hv = *reinterpret_cast<const v4f*>(hbp + i * 4);
        a0 = dot4f(xv, wi0[i], a0);
        a1 = dot4f(xv, wi1[i], a1);
        a2 = dot4f(xv, wi2[i], a2);
        a3 = dot4f(xv, wi3[i], a3);
        a4 = dot4f(hv, wh0[i], a4);
        a5 = dot4f(hv, wh1[i], a5);
        a6 = dot4f(hv, wh2[i], a6);
        a7 = dot4f(hv, wh3[i], a7);
      }
      a0 += __shfl_xor(a0, 16, 64); a0 += __shfl_xor(a0, 32, 64);
      a1 += __shfl_xor(a1, 16, 64); a1 += __shfl_xor(a1, 32, 64);
      a2 += __shfl_xor(a2, 16, 64); a2 += __shfl_xor(a2, 32, 64);
      a3 += __shfl_xor(a3, 16, 64); a3 += __shfl_xor(a3, 32, 64);
      a4 += __shfl_xor(a4, 16, 64); a4 += __shfl_xor(a4, 32, 64);
      a5 += __shfl_xor(a5, 16, 64); a5 += __shfl_xor(a5, 32, 64);
      a6 += __shfl_xor(a6, 16, 64); a6 += __shfl_xor(a6, 32, 64);
      a7 += __shfl_xor(a7, 16, 64); a7 += __shfl_xor(a7, 32, 64);
      if (q == 0) {
        gpart[wid][0][b] = a0; gpart[wid][1][b] = a1;
        gpart[wid][2][b] = a2; gpart[wid][3][b] = a3;
        gpart[wid][4][b] = a4; gpart[wid][5][b] = a5;
        gpart[wid][6][b] = a6; gpart[wid][7][b] = a7;
      }
    }
    __syncthreads();
    // (e) combine K-halves + LSTM pointwise (wave 0: lane = (jj=q, b))
    if (wid == 0) {
      const int jj = q;
      const int j  = bid * 4 + jj;
      float s0 = gpart[2*jj][0][b] + gpart[2*jj+1][0][b];
      float s1 = gpart[2*jj][1][b] + gpart[2*jj+1][1][b];
      float s2 = gpart[2*jj][2][b] + gpart[2*jj+1][2][b];
      float s3 = gpart[2*jj][3][b] + gpart[2*jj+1][3][b];
      float s4 = gpart[2*jj][4][b] + gpart[2*jj+1][4][b];
      float s5 = gpart[2*jj][5][b] + gpart[2*jj+1][5][b];
      float s6 = gpart[2*jj][6][b] + gpart[2*jj+1][6][b];
      float s7 = gpart[2*jj][7][b] + gpart[2*jj+1][7][b];
      float gi = s0 + s4 + bih[j]          + bhh[j];
      float gf = s1 + s5 + bih[Hh + j]     + bhh[Hh + j];
      float gg = s2 + s6 + bih[2*Hh + j]   + bhh[2*Hh + j];
      float go = s3 + s7 + bih[3*Hh + j]   + bhh[3*Hh + j];
      float cold = (t == 0) ? enc_c[b * Hh + j] : cbuf[b * Hh + j];
      float ig = 1.f / (1.f + expf(-gi));
      float fg = 1.f / (1.f + expf(-gf));
      float og = 1.f / (1.f + expf(-go));
      float cn = fg * cold + ig * tanhf(gg);
      float hn = og * tanhf(cn);
      cbuf[b * Hh + j] = cn;
      hcur[b * Hh + j] = hn;
    }
    grid_barrier(flags, gen, ++ep);

    // ================= phase B: logits =================
    for (int i = tid; i < Bb * (Hh / 4); i += NTHR) {
      int bb = i >> 8, k4 = i & 255;
      v4f hv = reinterpret_cast<const v4f*>(hcur + (size_t)bb * Hh)[k4];
      *reinterpret_cast<v4f*>(&h_sh[bb * PITCH + k4 * 4]) = hv;
    }
    __syncthreads();
    float mloc = -__builtin_inff(); float sloc = 0.f; int iloc = INT_MAX;
    if (wgl < 2000) {               // 2000 waves x 16 rows = 32000
      const float* hbp = &h_sh[b * PITCH + q * 256];
#pragma unroll
      for (int g = 0; g < 4; ++g) {
        size_t rbase = (size_t)wgl * 16 + g * 4;
        const v4f* w0 = reinterpret_cast<const v4f*>(Wlin) + rbase * 256 + q * 64;
        const v4f* w1 = w0 + 256;
        const v4f* w2 = w1 + 256;
        const v4f* w3 = w2 + 256;
        float a0=0, a1=0, a2=0, a3=0;
#pragma unroll 4
        for (int i = 0; i < 64; ++i) {
          v4f hv = *reinterpret_cast<const v4f*>(hbp + i * 4);
          a0 = dot4f(hv, w0[i], a0);
          a1 = dot4f(hv, w1[i], a1);
          a2 = dot4f(hv, w2[i], a2);
          a3 = dot4f(hv, w3[i], a3);
        }
        a0 += __shfl_xor(a0, 16, 64); a0 += __shfl_xor(a0, 32, 64);
        a1 += __shfl_xor(a1, 16, 64); a1 += __shfl_xor(a1, 32, 64);
        a2 += __shfl_xor(a2, 16, 64); a2 += __shfl_xor(a2, 32, 64);
        a3 += __shfl_xor(a3, 16, 64); a3 += __shfl_xor(a3, 32, 64);
        int rb0 = (int)rbase;
        a0 += blin[rb0]; a1 += blin[rb0+1]; a2 += blin[rb0+2]; a3 += blin[rb0+3];
        accL[g][0]=a0; accL[g][1]=a1; accL[g][2]=a2; accL[g][3]=a3;
        online_upd(mloc, sloc, iloc, a0, rb0);
        online_upd(mloc, sloc, iloc, a1, rb0+1);
        online_upd(mloc, sloc, iloc, a2, rb0+2);
        online_upd(mloc, sloc, iloc, a3, rb0+3);
      }
    }
    if (q == 0) { bm_[wid][b] = mloc; bs_[wid][b] = sloc; bi_[wid][b] = iloc; }
    __syncthreads();
    if (tid < Bb) {                  // block-level reduce: 8 waves -> 1 per batch
      float m = bm_[0][tid], s = bs_[0][tid]; int ix = bi_[0][tid];
#pragma unroll
      for (int w = 1; w < WPB; ++w) merge_ms(m, s, ix, bm_[w][tid], bs_[w][tid], bi_[w][tid]);
      pm[bid * Bb + tid] = m; ps[bid * Bb + tid] = s; pidx[bid * Bb + tid] = ix;
    }
    grid_barrier(flags, gen, ++ep);
  }

  // ===== tail: self-reduce norm for t=127, write final logits, h, c =====
  {
    int g = tid >> 5, l = tid & 31;
    float m = -__builtin_inff(); float s = 0.f; int ix = INT_MAX;
    for (int wb = l; wb < NBLK; wb += 32)
      merge_ms(m, s, ix, pm[wb * Bb + g], ps[wb * Bb + g], pidx[wb * Bb + g]);
#pragma unroll
    for (int off = 16; off; off >>= 1) {
      float m2 = __shfl_xor(m, off, 32);
      float s2 = __shfl_xor(s, off, 32);
      int   i2 = __shfl_xor(ix, off, 32);
      merge_ms(m, s, ix, m2, s2, i2);
    }
    if (l == 0) nm_sh[g] = m + logf(s);
  }
  __syncthreads();
  if (wgl < 2000 && q == 0) {
    float nb = nm_sh[b];
    size_t obase = ((size_t)b * Tt + (Tt - 1)) * (size_t)Vv;
#pragma unroll
    for (int g = 0; g < 4; ++g) {
      int rbase = wgl * 16 + g * 4;
      v4f vo;
      vo.x = accL[g][0] - nb; vo.y = accL[g][1] - nb;
      vo.z = accL[g][2] - nb; vo.w = accL[g][3] - nb;
      __builtin_nontemporal_store(vo, reinterpret_cast<v4f*>(out + obase + rbase));
    }
  }
  // h, c outputs (final h is hb1: step 127 is odd)
  const float* hfin = hb1;
  size_t tail = (size_t)Bb * Tt * Vv;
  for (int i = bid * NTHR + tid; i < Bb * Hh; i += NBLK * NTHR) {
    out[tail + i] = hfin[i];
    out[tail + Bb * Hh + i] = cbuf[i];
  }
}

extern "C" void kernel_launch(void* const* d_in, const int* in_sizes, int n_in,
                              void* d_out, int out_size, void* d_ws, size_t ws_size,
                              hipStream_t stream) {
  // inputs: 0 encoder_outputs (unused), 1 enc_h, 2 enc_c, 3 embedding,
  //         4 W_ih, 5 W_hh, 6 b_ih, 7 b_hh, 8 W_lin, 9 b_lin
  const float* enc_h = (const float*)d_in[1];
  const float* enc_c = (const float*)d_in[2];
  const float* emb   = (const float*)d_in[3];
  const float* Wih   = (const float*)d_in[4];
  const float* Whh   = (const float*)d_in[5];
  const float* bih   = (const float*)d_in[6];
  const float* bhh   = (const float*)d_in[7];
  const float* Wlin  = (const float*)d_in[8];
  const float* blin  = (const float*)d_in[9];
  float* out = (float*)d_out;

  char* ws = (char*)d_ws;
  int*   flags = (int*)ws;                          // 256 * 64B = 16 KB
  int*   gen   = (int*)(ws + 16384);                // own cacheline
  float* hb0   = (float*)(ws + 17408);
  float* hb1   = (float*)(ws + 17408 + 65536);
  float* cbuf  = (float*)(ws + 17408 + 131072);
  float* pm    = (float*)(ws + 17408 + 196608);     // 256*16 floats
  float* ps    = (float*)(ws + 17408 + 212992);
  int*   pidx  = (int*)  (ws + 17408 + 229376);
  // total ws use ~257 KB

  hipMemsetAsync(d_ws, 0, 16448, stream);           // zero flags + gen

  void* kargs[] = { (void*)&enc_h, (void*)&enc_c, (void*)&emb, (void*)&Wih,
                    (void*)&Whh, (void*)&bih, (void*)&bhh, (void*)&Wlin,
                    (void*)&blin, (void*)&out, (void*)&flags, (void*)&gen,
                    (void*)&hb0, (void*)&hb1, (void*)&cbuf,
                    (void*)&pm, (void*)&ps, (void*)&pidx };
  hipError_t e = hipLaunchCooperativeKernel((const void*)decoder_rnn_kernel,
                                            dim3(NBLK), dim3(NTHR), kargs, 0, stream);
  if (e != hipSuccess) {
    // fallback: plain launch (1 block/CU by LDS; co-residency expected)
    decoder_rnn_kernel<<<dim3(NBLK), dim3(NTHR), 0, stream>>>(
        enc_h, enc_c, emb, Wih, Whh, bih, bhh, Wlin, blin, out,
        flags, gen, hb0, hb1, cbuf, pm, ps, pidx);
  }
}